// Round 5
// baseline (342.843 us; speedup 1.0000x reference)
//
#include <hip/hip_runtime.h>

// out[N,32] = scatter_add over edges e: values[e] * x[cols[e], :] into row rows[e]
//
// Pipeline (bucket = row >> 5, 32 rows/bucket, nb = ceil(N/32) = 3125):
//   k1 hist : per-WG LDS histogram of buckets -> global bucket counts
//   k2 scan : single-WG exclusive scan (4 elems/thread, up to 4096) -> start, cursor
//   k3 bin  : WG-aggregated scatter of packed [val:32|col:17|rloc:5] records
//             into per-bucket contiguous runs
//   k4 spmm : ONE WG per 32-row bucket; streams only its own ~512 edges,
//             branch-free 4x-unrolled gather + LDS f32-atomic accumulate
//             into acc[32][33]; coalesced 32x32 block write. No global atomics.
//
// indices: d_in[0] = int[2*NNZ], values: d_in[1] = float[NNZ], x: d_in[2] = float[N*32]

#define D 32
#define BSHIFT 5
#define RPB 32                  // rows per bucket = 1 << BSHIFT
#define NB_MAX 4096
#define CHUNK 8192              // edges per workgroup in hist/bin

// ---------- k1: bucket histogram with LDS pre-aggregation ----------
__global__ __launch_bounds__(256) void hist_kernel(
    const int* __restrict__ idx, int* __restrict__ gcnt, int nnz, int nb)
{
    __shared__ int lcnt[NB_MAX];
    for (int i = threadIdx.x; i < nb; i += 256) lcnt[i] = 0;
    __syncthreads();
    int base = blockIdx.x * CHUNK;
    int end = min(base + CHUNK, nnz);
    for (int e = base + threadIdx.x; e < end; e += 256)
        atomicAdd(&lcnt[idx[e] >> BSHIFT], 1);
    __syncthreads();
    for (int i = threadIdx.x; i < nb; i += 256) {
        int c = lcnt[i];
        if (c) atomicAdd(&gcnt[i], c);
    }
}

// ---------- k2: exclusive scan, 4 elements per thread (nb <= 4096) ----------
__global__ __launch_bounds__(1024) void scan_kernel(
    const int* __restrict__ gcnt, int* __restrict__ start,
    int* __restrict__ gcursor, int nb)
{
    __shared__ int sm[1024];
    int base = threadIdx.x * 4;
    int v0 = (base + 0 < nb) ? gcnt[base + 0] : 0;
    int v1 = (base + 1 < nb) ? gcnt[base + 1] : 0;
    int v2 = (base + 2 < nb) ? gcnt[base + 2] : 0;
    int v3 = (base + 3 < nb) ? gcnt[base + 3] : 0;
    int tot = v0 + v1 + v2 + v3;
    sm[threadIdx.x] = tot;
    __syncthreads();
    for (int off = 1; off < 1024; off <<= 1) {
        int t = sm[threadIdx.x];
        int u = (threadIdx.x >= off) ? sm[threadIdx.x - off] : 0;
        __syncthreads();
        sm[threadIdx.x] = t + u;
        __syncthreads();
    }
    int ex = sm[threadIdx.x] - tot;          // exclusive prefix of this thread's 4
    int p0 = ex, p1 = ex + v0, p2 = p1 + v1, p3 = p2 + v2;
    if (base + 0 < nb) { start[base + 0] = p0; gcursor[base + 0] = p0; }
    if (base + 1 < nb) { start[base + 1] = p1; gcursor[base + 1] = p1; }
    if (base + 2 < nb) { start[base + 2] = p2; gcursor[base + 2] = p2; }
    if (base + 3 < nb) { start[base + 3] = p3; gcursor[base + 3] = p3; }
    if (threadIdx.x == 1023) start[nb] = sm[1023];
}

// ---------- k3: WG-aggregated bin scatter ----------
__global__ __launch_bounds__(256) void bin_kernel(
    const int* __restrict__ idx, const float* __restrict__ vals,
    int* __restrict__ gcursor, unsigned long long* __restrict__ packed,
    int nnz, int nb)
{
    __shared__ int lcnt[NB_MAX];
    __shared__ int lbase[NB_MAX];
    int base = blockIdx.x * CHUNK;
    int end = min(base + CHUNK, nnz);
    for (int i = threadIdx.x; i < nb; i += 256) lcnt[i] = 0;
    __syncthreads();
    for (int e = base + threadIdx.x; e < end; e += 256)
        atomicAdd(&lcnt[idx[e] >> BSHIFT], 1);
    __syncthreads();
    for (int i = threadIdx.x; i < nb; i += 256) {
        int c = lcnt[i];
        lbase[i] = c ? atomicAdd(&gcursor[i], c) : 0;
        lcnt[i] = 0;                       // reuse as intra-WG cursor
    }
    __syncthreads();
    for (int e = base + threadIdx.x; e < end; e += 256) {
        int r = idx[e];
        int b = r >> BSHIFT;
        int pos = lbase[b] + atomicAdd(&lcnt[b], 1);
        unsigned c = (unsigned)idx[nnz + e];
        unsigned vb = __float_as_uint(vals[e]);
        packed[pos] = ((unsigned long long)vb << 32)
                    | ((unsigned long long)c << BSHIFT) | (unsigned)(r & (RPB - 1));
    }
}

// ---------- k4: one WG per 32-row bucket, branch-free 4x-unrolled ----------
__global__ __launch_bounds__(256) void spmm32_kernel(
    const int* __restrict__ bucket_start,
    const unsigned long long* __restrict__ packed,
    const float* __restrict__ x, float* __restrict__ out, int N)
{
    __shared__ float acc[RPB * 33];        // +1 pad breaks bank aliasing
    for (int i = threadIdx.x; i < RPB * 33; i += 256) acc[i] = 0.f;
    __syncthreads();

    int b = blockIdx.x;
    int s = bucket_start[b];
    int e = bucket_start[b + 1];
    int g = threadIdx.x >> 3;              // 32 edge-groups of 8 lanes
    int q = threadIdx.x & 7;               // 4 columns each
    const float4* __restrict__ x4 = reinterpret_cast<const float4*>(x);

    int k = s + g;
    for (; k + 96 < e; k += 128) {         // 4 independent load->gather chains
        unsigned long long p0 = packed[k];
        unsigned long long p1 = packed[k + 32];
        unsigned long long p2 = packed[k + 64];
        unsigned long long p3 = packed[k + 96];
        int rl0 = (int)(p0 & (RPB - 1)), c0 = (int)((p0 >> BSHIFT) & 0x1ffff);
        int rl1 = (int)(p1 & (RPB - 1)), c1 = (int)((p1 >> BSHIFT) & 0x1ffff);
        int rl2 = (int)(p2 & (RPB - 1)), c2 = (int)((p2 >> BSHIFT) & 0x1ffff);
        int rl3 = (int)(p3 & (RPB - 1)), c3 = (int)((p3 >> BSHIFT) & 0x1ffff);
        float v0 = __uint_as_float((unsigned)(p0 >> 32));
        float v1 = __uint_as_float((unsigned)(p1 >> 32));
        float v2 = __uint_as_float((unsigned)(p2 >> 32));
        float v3 = __uint_as_float((unsigned)(p3 >> 32));
        float4 a0 = x4[(size_t)c0 * (D / 4) + q];
        float4 a1 = x4[(size_t)c1 * (D / 4) + q];
        float4 a2 = x4[(size_t)c2 * (D / 4) + q];
        float4 a3 = x4[(size_t)c3 * (D / 4) + q];
        float* d0 = &acc[rl0 * 33 + q * 4];
        atomicAdd(d0 + 0, v0 * a0.x); atomicAdd(d0 + 1, v0 * a0.y);
        atomicAdd(d0 + 2, v0 * a0.z); atomicAdd(d0 + 3, v0 * a0.w);
        float* d1 = &acc[rl1 * 33 + q * 4];
        atomicAdd(d1 + 0, v1 * a1.x); atomicAdd(d1 + 1, v1 * a1.y);
        atomicAdd(d1 + 2, v1 * a1.z); atomicAdd(d1 + 3, v1 * a1.w);
        float* d2 = &acc[rl2 * 33 + q * 4];
        atomicAdd(d2 + 0, v2 * a2.x); atomicAdd(d2 + 1, v2 * a2.y);
        atomicAdd(d2 + 2, v2 * a2.z); atomicAdd(d2 + 3, v2 * a2.w);
        float* d3 = &acc[rl3 * 33 + q * 4];
        atomicAdd(d3 + 0, v3 * a3.x); atomicAdd(d3 + 1, v3 * a3.y);
        atomicAdd(d3 + 2, v3 * a3.z); atomicAdd(d3 + 3, v3 * a3.w);
    }
    for (; k < e; k += 32) {
        unsigned long long p = packed[k];
        int rl = (int)(p & (RPB - 1)), c = (int)((p >> BSHIFT) & 0x1ffff);
        float v = __uint_as_float((unsigned)(p >> 32));
        float4 a = x4[(size_t)c * (D / 4) + q];
        float* d = &acc[rl * 33 + q * 4];
        atomicAdd(d + 0, v * a.x); atomicAdd(d + 1, v * a.y);
        atomicAdd(d + 2, v * a.z); atomicAdd(d + 3, v * a.w);
    }
    __syncthreads();

    int row0 = b << BSHIFT;
    int lim = min(RPB, N - row0);
    if (lim > 0)
        for (int i = threadIdx.x; i < lim * D; i += 256)
            out[(size_t)row0 * D + i] = acc[(i >> 5) * 33 + (i & 31)];
}

// ---------- fallback: direct atomic scatter (round-1) ----------
__global__ __launch_bounds__(256) void spmm_scatter_kernel(
    const int* __restrict__ idx, const float* __restrict__ vals,
    const float* __restrict__ x, float* __restrict__ out, int nnz)
{
    int t = blockIdx.x * blockDim.x + threadIdx.x;
    int e = t >> 3;
    int q = t & 7;
    if (e >= nnz) return;
    int r = idx[e];
    int c = idx[nnz + e];
    float v = vals[e];
    const float4 xv = reinterpret_cast<const float4*>(x)[(size_t)c * (D / 4) + q];
    float* o = out + (size_t)r * D + q * 4;
    atomicAdd(o + 0, v * xv.x);
    atomicAdd(o + 1, v * xv.y);
    atomicAdd(o + 2, v * xv.z);
    atomicAdd(o + 3, v * xv.w);
}

static inline size_t align256(size_t v) { return (v + 255) & ~(size_t)255; }

extern "C" void kernel_launch(void* const* d_in, const int* in_sizes, int n_in,
                              void* d_out, int out_size, void* d_ws, size_t ws_size,
                              hipStream_t stream)
{
    const int* idx   = (const int*)d_in[0];
    const float* val = (const float*)d_in[1];
    const float* x   = (const float*)d_in[2];
    float* out       = (float*)d_out;

    const int nnz = in_sizes[1];
    const int N   = out_size / D;
    const int nb  = (N + RPB - 1) >> BSHIFT;

    size_t off_cnt    = 0;
    size_t off_start  = align256(off_cnt    + (size_t)nb * 4);
    size_t off_cursor = align256(off_start  + (size_t)(nb + 1) * 4);
    size_t off_packed = align256(off_cursor + (size_t)nb * 4);
    size_t ws_needed  = off_packed + (size_t)nnz * 8;

    // col must fit 17 bits, nb must fit scan width
    if (ws_size < ws_needed || nb > NB_MAX || N > 131072) {
        hipMemsetAsync(d_out, 0, (size_t)out_size * sizeof(float), stream);
        const long long total = (long long)nnz * 8;
        spmm_scatter_kernel<<<(int)((total + 255) / 256), 256, 0, stream>>>(
            idx, val, x, out, nnz);
        return;
    }

    char* ws = (char*)d_ws;
    int* gcnt    = (int*)(ws + off_cnt);
    int* start   = (int*)(ws + off_start);
    int* gcursor = (int*)(ws + off_cursor);
    unsigned long long* packed = (unsigned long long*)(ws + off_packed);

    hipMemsetAsync(gcnt, 0, (size_t)nb * 4, stream);

    const int nchunk = (nnz + CHUNK - 1) / CHUNK;
    hist_kernel<<<nchunk, 256, 0, stream>>>(idx, gcnt, nnz, nb);
    scan_kernel<<<1, 1024, 0, stream>>>(gcnt, start, gcursor, nb);
    bin_kernel<<<nchunk, 256, 0, stream>>>(idx, val, gcursor, packed, nnz, nb);
    spmm32_kernel<<<nb, 256, 0, stream>>>(start, packed, x, out, N);
}

// Round 6
// 97.626 us; speedup vs baseline: 3.5118x; 3.5118x over previous
//
#include <hip/hip_runtime.h>

// out[N,32] = scatter_add over edges e: values[e] * x[cols[e], :] into row rows[e]
//
// Pipeline (bucket = row >> 5, 32 rows/bucket, nb = ceil(N/32) = 3125):
//   k1 hist : per-WG LDS histogram of buckets -> global bucket counts
//   k2 scan : single-WG exclusive scan (4 elems/thread, up to 4096) -> start, cursor
//   k3 bin  : WG-aggregated scatter of packed [val:32|col:17|rloc:5] records
//             into per-bucket contiguous runs
//   k4 spmm : one WG per 32-row bucket. Per 1024-edge chunk: LDS counting sort
//             by row (hist 32 counters -> shuffle scan -> scatter), then each
//             8-lane group owns ONE row and accumulates in REGISTERS (float4,
//             4 gather chains in flight) — zero per-edge atomics anywhere.
//
// indices: d_in[0] = int[2*NNZ], values: d_in[1] = float[NNZ], x: d_in[2] = float[N*32]

#define D 32
#define BSHIFT 5
#define RPB 32                  // rows per bucket = 1 << BSHIFT
#define NB_MAX 4096
#define CHUNK 4096              // edges per workgroup in hist/bin
#define MAXE 1024               // sort-chunk size in spmm (regs: MAXE/256 = 4 per thread)

typedef unsigned long long ull;

// ---------- k1: bucket histogram with LDS pre-aggregation ----------
__global__ __launch_bounds__(256) void hist_kernel(
    const int* __restrict__ idx, int* __restrict__ gcnt, int nnz, int nb)
{
    __shared__ int lcnt[NB_MAX];
    for (int i = threadIdx.x; i < nb; i += 256) lcnt[i] = 0;
    __syncthreads();
    int base = blockIdx.x * CHUNK;
    int end = min(base + CHUNK, nnz);
    for (int e = base + threadIdx.x; e < end; e += 256)
        atomicAdd(&lcnt[idx[e] >> BSHIFT], 1);
    __syncthreads();
    for (int i = threadIdx.x; i < nb; i += 256) {
        int c = lcnt[i];
        if (c) atomicAdd(&gcnt[i], c);
    }
}

// ---------- k2: exclusive scan, 4 elements per thread (nb <= 4096) ----------
__global__ __launch_bounds__(1024) void scan_kernel(
    const int* __restrict__ gcnt, int* __restrict__ start,
    int* __restrict__ gcursor, int nb)
{
    __shared__ int sm[1024];
    int base = threadIdx.x * 4;
    int v0 = (base + 0 < nb) ? gcnt[base + 0] : 0;
    int v1 = (base + 1 < nb) ? gcnt[base + 1] : 0;
    int v2 = (base + 2 < nb) ? gcnt[base + 2] : 0;
    int v3 = (base + 3 < nb) ? gcnt[base + 3] : 0;
    int tot = v0 + v1 + v2 + v3;
    sm[threadIdx.x] = tot;
    __syncthreads();
    for (int off = 1; off < 1024; off <<= 1) {
        int t = sm[threadIdx.x];
        int u = (threadIdx.x >= off) ? sm[threadIdx.x - off] : 0;
        __syncthreads();
        sm[threadIdx.x] = t + u;
        __syncthreads();
    }
    int ex = sm[threadIdx.x] - tot;          // exclusive prefix of this thread's 4
    int p0 = ex, p1 = ex + v0, p2 = p1 + v1, p3 = p2 + v2;
    if (base + 0 < nb) { start[base + 0] = p0; gcursor[base + 0] = p0; }
    if (base + 1 < nb) { start[base + 1] = p1; gcursor[base + 1] = p1; }
    if (base + 2 < nb) { start[base + 2] = p2; gcursor[base + 2] = p2; }
    if (base + 3 < nb) { start[base + 3] = p3; gcursor[base + 3] = p3; }
    if (threadIdx.x == 1023) start[nb] = sm[1023];
}

// ---------- k3: WG-aggregated bin scatter ----------
__global__ __launch_bounds__(256) void bin_kernel(
    const int* __restrict__ idx, const float* __restrict__ vals,
    int* __restrict__ gcursor, ull* __restrict__ packed,
    int nnz, int nb)
{
    __shared__ int lcnt[NB_MAX];
    __shared__ int lbase[NB_MAX];
    int base = blockIdx.x * CHUNK;
    int end = min(base + CHUNK, nnz);
    for (int i = threadIdx.x; i < nb; i += 256) lcnt[i] = 0;
    __syncthreads();
    for (int e = base + threadIdx.x; e < end; e += 256)
        atomicAdd(&lcnt[idx[e] >> BSHIFT], 1);
    __syncthreads();
    for (int i = threadIdx.x; i < nb; i += 256) {
        int c = lcnt[i];
        lbase[i] = c ? atomicAdd(&gcursor[i], c) : 0;
        lcnt[i] = 0;                       // reuse as intra-WG cursor
    }
    __syncthreads();
    for (int e = base + threadIdx.x; e < end; e += 256) {
        int r = idx[e];
        int b = r >> BSHIFT;
        int pos = lbase[b] + atomicAdd(&lcnt[b], 1);
        unsigned c = (unsigned)idx[nnz + e];
        unsigned vb = __float_as_uint(vals[e]);
        packed[pos] = ((ull)vb << 32) | ((ull)c << BSHIFT) | (unsigned)(r & (RPB - 1));
    }
}

// ---------- k4: counting-sort + register-accumulate SpMM ----------
__global__ __launch_bounds__(256) void spmm_sort_kernel(
    const int* __restrict__ bucket_start,
    const ull* __restrict__ packed,
    const float* __restrict__ x, float* __restrict__ out, int N)
{
    __shared__ ull sp[MAXE];       // row-sorted chunk
    __shared__ int cnt[RPB];
    __shared__ int off[RPB];
    __shared__ int cur[RPB];

    int b = blockIdx.x;
    int s = bucket_start[b];
    int e = bucket_start[b + 1];
    int g = threadIdx.x >> 3;      // group = owned row-local index (32 groups)
    int q = threadIdx.x & 7;       // 4 columns each
    const float4* __restrict__ x4 = reinterpret_cast<const float4*>(x);

    float4 acc = make_float4(0.f, 0.f, 0.f, 0.f);

    for (int base = s; base < e; base += MAXE) {
        int m = min(MAXE, e - base);

        if (threadIdx.x < RPB) cnt[threadIdx.x] = 0;
        __syncthreads();

        // hist (keep entries in registers for the scatter pass)
        ull pv[MAXE / 256];
        int have[MAXE / 256];
        #pragma unroll
        for (int j = 0; j < MAXE / 256; ++j) {
            int i = threadIdx.x + j * 256;
            have[j] = (i < m);
            if (have[j]) {
                pv[j] = packed[base + i];
                atomicAdd(&cnt[(int)(pv[j] & (RPB - 1))], 1);
            }
        }
        __syncthreads();

        // exclusive scan of 32 counters (lanes 0..31 of wave 0, shuffle scan)
        if (threadIdx.x < RPB) {
            int v = cnt[threadIdx.x];
            int sum = v;
            #pragma unroll
            for (int d = 1; d < RPB; d <<= 1) {
                int u = __shfl_up(sum, d, 64);
                if ((int)threadIdx.x >= d) sum += u;
            }
            off[threadIdx.x] = sum - v;
            cur[threadIdx.x] = sum - v;
        }
        __syncthreads();

        // scatter into row-sorted order
        #pragma unroll
        for (int j = 0; j < MAXE / 256; ++j) {
            if (have[j]) {
                int rl = (int)(pv[j] & (RPB - 1));
                int pos = atomicAdd(&cur[rl], 1);
                sp[pos] = pv[j];
            }
        }
        __syncthreads();

        // group g accumulates its own row's segment — registers, no atomics
        int rs = off[g];
        int re = rs + cnt[g];
        int k = rs;
        for (; k + 3 < re; k += 4) {       // 4 gathers in flight
            ull p0 = sp[k], p1 = sp[k + 1], p2 = sp[k + 2], p3 = sp[k + 3];
            int c0 = (int)((p0 >> BSHIFT) & 0x1ffff);
            int c1 = (int)((p1 >> BSHIFT) & 0x1ffff);
            int c2 = (int)((p2 >> BSHIFT) & 0x1ffff);
            int c3 = (int)((p3 >> BSHIFT) & 0x1ffff);
            float v0 = __uint_as_float((unsigned)(p0 >> 32));
            float v1 = __uint_as_float((unsigned)(p1 >> 32));
            float v2 = __uint_as_float((unsigned)(p2 >> 32));
            float v3 = __uint_as_float((unsigned)(p3 >> 32));
            float4 a0 = x4[(size_t)c0 * (D / 4) + q];
            float4 a1 = x4[(size_t)c1 * (D / 4) + q];
            float4 a2 = x4[(size_t)c2 * (D / 4) + q];
            float4 a3 = x4[(size_t)c3 * (D / 4) + q];
            acc.x += v0 * a0.x; acc.y += v0 * a0.y; acc.z += v0 * a0.z; acc.w += v0 * a0.w;
            acc.x += v1 * a1.x; acc.y += v1 * a1.y; acc.z += v1 * a1.z; acc.w += v1 * a1.w;
            acc.x += v2 * a2.x; acc.y += v2 * a2.y; acc.z += v2 * a2.z; acc.w += v2 * a2.w;
            acc.x += v3 * a3.x; acc.y += v3 * a3.y; acc.z += v3 * a3.z; acc.w += v3 * a3.w;
        }
        for (; k < re; ++k) {
            ull p = sp[k];
            int c = (int)((p >> BSHIFT) & 0x1ffff);
            float v = __uint_as_float((unsigned)(p >> 32));
            float4 a = x4[(size_t)c * (D / 4) + q];
            acc.x += v * a.x; acc.y += v * a.y; acc.z += v * a.z; acc.w += v * a.w;
        }
        __syncthreads();   // protect sp/cnt before next chunk
    }

    int row = (b << BSHIFT) + g;
    if (row < N)
        reinterpret_cast<float4*>(out)[(size_t)row * (D / 4) + q] = acc;
}

// ---------- fallback: direct atomic scatter (round-1) ----------
__global__ __launch_bounds__(256) void spmm_scatter_kernel(
    const int* __restrict__ idx, const float* __restrict__ vals,
    const float* __restrict__ x, float* __restrict__ out, int nnz)
{
    int t = blockIdx.x * blockDim.x + threadIdx.x;
    int e = t >> 3;
    int q = t & 7;
    if (e >= nnz) return;
    int r = idx[e];
    int c = idx[nnz + e];
    float v = vals[e];
    const float4 xv = reinterpret_cast<const float4*>(x)[(size_t)c * (D / 4) + q];
    float* o = out + (size_t)r * D + q * 4;
    atomicAdd(o + 0, v * xv.x);
    atomicAdd(o + 1, v * xv.y);
    atomicAdd(o + 2, v * xv.z);
    atomicAdd(o + 3, v * xv.w);
}

static inline size_t align256(size_t v) { return (v + 255) & ~(size_t)255; }

extern "C" void kernel_launch(void* const* d_in, const int* in_sizes, int n_in,
                              void* d_out, int out_size, void* d_ws, size_t ws_size,
                              hipStream_t stream)
{
    const int* idx   = (const int*)d_in[0];
    const float* val = (const float*)d_in[1];
    const float* x   = (const float*)d_in[2];
    float* out       = (float*)d_out;

    const int nnz = in_sizes[1];
    const int N   = out_size / D;
    const int nb  = (N + RPB - 1) >> BSHIFT;

    size_t off_cnt    = 0;
    size_t off_start  = align256(off_cnt    + (size_t)nb * 4);
    size_t off_cursor = align256(off_start  + (size_t)(nb + 1) * 4);
    size_t off_packed = align256(off_cursor + (size_t)nb * 4);
    size_t ws_needed  = off_packed + (size_t)nnz * 8;

    // col must fit 17 bits, nb must fit scan width
    if (ws_size < ws_needed || nb > NB_MAX || N > 131072) {
        hipMemsetAsync(d_out, 0, (size_t)out_size * sizeof(float), stream);
        const long long total = (long long)nnz * 8;
        spmm_scatter_kernel<<<(int)((total + 255) / 256), 256, 0, stream>>>(
            idx, val, x, out, nnz);
        return;
    }

    char* ws = (char*)d_ws;
    int* gcnt    = (int*)(ws + off_cnt);
    int* start   = (int*)(ws + off_start);
    int* gcursor = (int*)(ws + off_cursor);
    ull* packed  = (ull*)(ws + off_packed);

    hipMemsetAsync(gcnt, 0, (size_t)nb * 4, stream);

    const int nchunk = (nnz + CHUNK - 1) / CHUNK;
    hist_kernel<<<nchunk, 256, 0, stream>>>(idx, gcnt, nnz, nb);
    scan_kernel<<<1, 1024, 0, stream>>>(gcnt, start, gcursor, nb);
    bin_kernel<<<nchunk, 256, 0, stream>>>(idx, val, gcursor, packed, nnz, nb);
    spmm_sort_kernel<<<nb, 256, 0, stream>>>(start, packed, x, out, N);
}

// Round 7
// 94.169 us; speedup vs baseline: 3.6407x; 1.0367x over previous
//
#include <hip/hip_runtime.h>

// out[N,32] = scatter_add over edges e: values[e] * x[cols[e], :] into row rows[e]
//
// Pipeline (superbucket = row >> 7, 128 rows, nb128 = ceil(N/128) = 782):
//   k1 hist128 : per-WG LDS histogram of superbuckets -> global counts
//   k2 scan128 : single-WG exclusive scan (782 <= 1024) -> sstart, cursor
//   k3 bin1    : WG-aggregated scatter of packed [val:32|col:17|rloc:7] records
//                into superbucket runs (~5 edge runs -> moderate write-amp)
//   k4 spmm4   : FOUR WGs per superbucket (grid = nb32 = 3125). Each WG streams
//                the full run, keeps only entries with rloc7>>5 == its sub-slot,
//                LDS counting-sorts them by the low 5 row bits, then each 8-lane
//                group owns ONE row and accumulates in registers. No atomics on
//                any per-edge float anywhere.
//
// indices: d_in[0] = int[2*NNZ], values: d_in[1] = float[NNZ], x: d_in[2] = float[N*32]

#define D 32
#define SBSHIFT 7
#define BSHIFT 5
#define RPB 32                  // rows per spmm bucket
#define NB128_MAX 1024
#define CHUNK 4096              // edges per workgroup in hist/bin
#define MAXE 1024               // sort-chunk size in spmm

typedef unsigned long long ull;

// ---------- k1: superbucket histogram with LDS pre-aggregation ----------
__global__ __launch_bounds__(256) void hist128_kernel(
    const int* __restrict__ idx, int* __restrict__ gcnt, int nnz, int nb)
{
    __shared__ int lcnt[NB128_MAX];
    for (int i = threadIdx.x; i < nb; i += 256) lcnt[i] = 0;
    __syncthreads();
    int base = blockIdx.x * CHUNK;
    int end = min(base + CHUNK, nnz);
    for (int e = base + threadIdx.x; e < end; e += 256)
        atomicAdd(&lcnt[idx[e] >> SBSHIFT], 1);
    __syncthreads();
    for (int i = threadIdx.x; i < nb; i += 256) {
        int c = lcnt[i];
        if (c) atomicAdd(&gcnt[i], c);
    }
}

// ---------- k2: exclusive scan of superbucket counts (nb <= 1024) ----------
__global__ __launch_bounds__(1024) void scan128_kernel(
    const int* __restrict__ gcnt, int* __restrict__ sstart,
    int* __restrict__ cursor, int nb)
{
    __shared__ int sm[1024];
    int v = ((int)threadIdx.x < nb) ? gcnt[threadIdx.x] : 0;
    sm[threadIdx.x] = v;
    __syncthreads();
    for (int off = 1; off < 1024; off <<= 1) {
        int t = sm[threadIdx.x];
        int u = ((int)threadIdx.x >= off) ? sm[threadIdx.x - off] : 0;
        __syncthreads();
        sm[threadIdx.x] = t + u;
        __syncthreads();
    }
    if ((int)threadIdx.x < nb) {
        int ex = sm[threadIdx.x] - v;
        sstart[threadIdx.x] = ex;
        cursor[threadIdx.x] = ex;
    }
    if (threadIdx.x == 1023) sstart[nb] = sm[1023];
}

// ---------- k3: WG-aggregated bin scatter into superbucket runs ----------
__global__ __launch_bounds__(256) void bin1_kernel(
    const int* __restrict__ idx, const float* __restrict__ vals,
    int* __restrict__ gcursor, ull* __restrict__ packed,
    int nnz, int nb)
{
    __shared__ int lcnt[NB128_MAX];
    __shared__ int lbase[NB128_MAX];
    int base = blockIdx.x * CHUNK;
    int end = min(base + CHUNK, nnz);
    for (int i = threadIdx.x; i < nb; i += 256) lcnt[i] = 0;
    __syncthreads();
    for (int e = base + threadIdx.x; e < end; e += 256)
        atomicAdd(&lcnt[idx[e] >> SBSHIFT], 1);
    __syncthreads();
    for (int i = threadIdx.x; i < nb; i += 256) {
        int c = lcnt[i];
        lbase[i] = c ? atomicAdd(&gcursor[i], c) : 0;
        lcnt[i] = 0;                       // reuse as intra-WG cursor
    }
    __syncthreads();
    for (int e = base + threadIdx.x; e < end; e += 256) {
        int r = idx[e];
        int b = r >> SBSHIFT;
        int pos = lbase[b] + atomicAdd(&lcnt[b], 1);
        unsigned c = (unsigned)idx[nnz + e];
        unsigned vb = __float_as_uint(vals[e]);
        packed[pos] = ((ull)vb << 32) | ((ull)c << SBSHIFT) | (unsigned)(r & 127);
    }
}

// ---------- k4: filtered counting-sort + register-accumulate SpMM ----------
__global__ __launch_bounds__(256) void spmm4_kernel(
    const int* __restrict__ sstart,
    const ull* __restrict__ packed,
    const float* __restrict__ x, float* __restrict__ out, int N)
{
    __shared__ ull sp[MAXE];       // row-sorted slice of this chunk
    __shared__ int cnt[RPB];
    __shared__ int off[RPB];
    __shared__ int cur[RPB];

    int b = blockIdx.x;            // 32-row bucket id
    int j = b >> 2;                // superbucket
    int mysub = b & 3;             // which 32-row slice of the 128
    int s = sstart[j];
    int e = sstart[j + 1];
    int g = threadIdx.x >> 3;      // group = owned row-local index (32 groups)
    int q = threadIdx.x & 7;       // 4 columns each
    const float4* __restrict__ x4 = reinterpret_cast<const float4*>(x);

    float4 acc = make_float4(0.f, 0.f, 0.f, 0.f);

    for (int base = s; base < e; base += MAXE) {
        int m = min(MAXE, e - base);

        if (threadIdx.x < RPB) cnt[threadIdx.x] = 0;
        __syncthreads();

        // filtered hist (keep matching entries in registers for the scatter pass)
        ull pv[MAXE / 256];
        bool have[MAXE / 256];
        #pragma unroll
        for (int jj = 0; jj < MAXE / 256; ++jj) {
            int i = threadIdx.x + jj * 256;
            have[jj] = false;
            if (i < m) {
                ull p = packed[base + i];
                if ((int)((p >> BSHIFT) & 3) == mysub) {   // bits 5..6 of rloc7
                    pv[jj] = p;
                    have[jj] = true;
                    atomicAdd(&cnt[(int)(p & (RPB - 1))], 1);
                }
            }
        }
        __syncthreads();

        // exclusive scan of 32 counters (lanes 0..31 of wave 0)
        if (threadIdx.x < RPB) {
            int v = cnt[threadIdx.x];
            int sum = v;
            #pragma unroll
            for (int d = 1; d < RPB; d <<= 1) {
                int u = __shfl_up(sum, d, 64);
                if ((int)threadIdx.x >= d) sum += u;
            }
            off[threadIdx.x] = sum - v;
            cur[threadIdx.x] = sum - v;
        }
        __syncthreads();

        // scatter my slice into row-sorted order
        #pragma unroll
        for (int jj = 0; jj < MAXE / 256; ++jj) {
            if (have[jj]) {
                int rl = (int)(pv[jj] & (RPB - 1));
                int pos = atomicAdd(&cur[rl], 1);
                sp[pos] = pv[jj];
            }
        }
        __syncthreads();

        // group g accumulates its own row's segment — registers, no atomics
        int rs = off[g];
        int re = rs + cnt[g];
        int k = rs;
        for (; k + 3 < re; k += 4) {       // 4 gathers in flight
            ull p0 = sp[k], p1 = sp[k + 1], p2 = sp[k + 2], p3 = sp[k + 3];
            int c0 = (int)((p0 >> SBSHIFT) & 0x1ffff);
            int c1 = (int)((p1 >> SBSHIFT) & 0x1ffff);
            int c2 = (int)((p2 >> SBSHIFT) & 0x1ffff);
            int c3 = (int)((p3 >> SBSHIFT) & 0x1ffff);
            float v0 = __uint_as_float((unsigned)(p0 >> 32));
            float v1 = __uint_as_float((unsigned)(p1 >> 32));
            float v2 = __uint_as_float((unsigned)(p2 >> 32));
            float v3 = __uint_as_float((unsigned)(p3 >> 32));
            float4 a0 = x4[(size_t)c0 * (D / 4) + q];
            float4 a1 = x4[(size_t)c1 * (D / 4) + q];
            float4 a2 = x4[(size_t)c2 * (D / 4) + q];
            float4 a3 = x4[(size_t)c3 * (D / 4) + q];
            acc.x += v0 * a0.x; acc.y += v0 * a0.y; acc.z += v0 * a0.z; acc.w += v0 * a0.w;
            acc.x += v1 * a1.x; acc.y += v1 * a1.y; acc.z += v1 * a1.z; acc.w += v1 * a1.w;
            acc.x += v2 * a2.x; acc.y += v2 * a2.y; acc.z += v2 * a2.z; acc.w += v2 * a2.w;
            acc.x += v3 * a3.x; acc.y += v3 * a3.y; acc.z += v3 * a3.z; acc.w += v3 * a3.w;
        }
        for (; k < re; ++k) {
            ull p = sp[k];
            int c = (int)((p >> SBSHIFT) & 0x1ffff);
            float v = __uint_as_float((unsigned)(p >> 32));
            float4 a = x4[(size_t)c * (D / 4) + q];
            acc.x += v * a.x; acc.y += v * a.y; acc.z += v * a.z; acc.w += v * a.w;
        }
        __syncthreads();   // protect sp/cnt before next chunk
    }

    int row = (j << SBSHIFT) + (mysub << BSHIFT) + g;
    if (row < N)
        reinterpret_cast<float4*>(out)[(size_t)row * (D / 4) + q] = acc;
}

// ---------- fallback: direct atomic scatter (round-1) ----------
__global__ __launch_bounds__(256) void spmm_scatter_kernel(
    const int* __restrict__ idx, const float* __restrict__ vals,
    const float* __restrict__ x, float* __restrict__ out, int nnz)
{
    int t = blockIdx.x * blockDim.x + threadIdx.x;
    int e = t >> 3;
    int q = t & 7;
    if (e >= nnz) return;
    int r = idx[e];
    int c = idx[nnz + e];
    float v = vals[e];
    const float4 xv = reinterpret_cast<const float4*>(x)[(size_t)c * (D / 4) + q];
    float* o = out + (size_t)r * D + q * 4;
    atomicAdd(o + 0, v * xv.x);
    atomicAdd(o + 1, v * xv.y);
    atomicAdd(o + 2, v * xv.z);
    atomicAdd(o + 3, v * xv.w);
}

static inline size_t align256(size_t v) { return (v + 255) & ~(size_t)255; }

extern "C" void kernel_launch(void* const* d_in, const int* in_sizes, int n_in,
                              void* d_out, int out_size, void* d_ws, size_t ws_size,
                              hipStream_t stream)
{
    const int* idx   = (const int*)d_in[0];
    const float* val = (const float*)d_in[1];
    const float* x   = (const float*)d_in[2];
    float* out       = (float*)d_out;

    const int nnz  = in_sizes[1];
    const int N    = out_size / D;
    const int nb128 = (N + 127) >> SBSHIFT;   // superbuckets
    const int nb32  = (N + 31) >> BSHIFT;     // spmm buckets (grid)

    size_t off_cnt    = 0;
    size_t off_sstart = align256(off_cnt    + (size_t)nb128 * 4);
    size_t off_cursor = align256(off_sstart + (size_t)(nb128 + 1) * 4);
    size_t off_packed = align256(off_cursor + (size_t)nb128 * 4);
    size_t ws_needed  = off_packed + (size_t)nnz * 8;

    // col must fit 17 bits, nb128 must fit scan width
    if (ws_size < ws_needed || nb128 > NB128_MAX || N > 131072) {
        hipMemsetAsync(d_out, 0, (size_t)out_size * sizeof(float), stream);
        const long long total = (long long)nnz * 8;
        spmm_scatter_kernel<<<(int)((total + 255) / 256), 256, 0, stream>>>(
            idx, val, x, out, nnz);
        return;
    }

    char* ws = (char*)d_ws;
    int* gcnt   = (int*)(ws + off_cnt);
    int* sstart = (int*)(ws + off_sstart);
    int* cursor = (int*)(ws + off_cursor);
    ull* packed = (ull*)(ws + off_packed);

    hipMemsetAsync(gcnt, 0, (size_t)nb128 * 4, stream);

    const int nchunk = (nnz + CHUNK - 1) / CHUNK;
    hist128_kernel<<<nchunk, 256, 0, stream>>>(idx, gcnt, nnz, nb128);
    scan128_kernel<<<1, 1024, 0, stream>>>(gcnt, sstart, cursor, nb128);
    bin1_kernel<<<nchunk, 256, 0, stream>>>(idx, val, cursor, packed, nnz, nb128);
    spmm4_kernel<<<nb32, 256, 0, stream>>>(sstart, packed, x, out, N);
}